// Round 10
// baseline (59.427 us; speedup 1.0000x reference)
//
#include <hip/hip_runtime.h>
#include <hip/hip_bf16.h>

#define NN 4096
#define EMB 256
#define NCH 10
#define TOTD 2560  // NCH*EMB

typedef __attribute__((ext_vector_type(4))) float f32x4;
typedef __attribute__((ext_vector_type(16))) float f32x16;
typedef __attribute__((ext_vector_type(4))) int i32x4;
typedef __attribute__((ext_vector_type(8))) int i32x8;

#define AS1 __attribute__((address_space(1)))
#define AS3 __attribute__((address_space(3)))

__device__ __forceinline__ void gload_lds16(const void* g, void* l) {
    __builtin_amdgcn_global_load_lds((const AS1 unsigned int*)g,
                                     (AS3 unsigned int*)l, 16, 0, 0);
}

// float -> OCP e4m3fn, RNE, flush |x| < 2^-6 (min normal) to 0.
__device__ __forceinline__ unsigned int f32_to_e4m3(float x) {
    unsigned int u = __float_as_uint(x);
    if ((u & 0x7FFFFFFFu) < 0x3C800000u) return 0u;   // |x| < 2^-6
    unsigned int r = u + 0x7FFFFu + ((u >> 20) & 1u); // RNE to 3 mantissa bits
    unsigned int s = (u >> 31) << 7;
    unsigned int e = (r >> 23) & 0xFFu;
    unsigned int m3 = (r >> 20) & 7u;
    return s | ((e - 120u) << 3) | m3;
}

// ---- kernel 1 (fused prep): one pass over E.
__global__ __launch_bounds__(256) void prep_k(const float* __restrict__ E,
                                              const float* __restrict__ w,
                                              unsigned char* __restrict__ Gt8,
                                              float* __restrict__ csp) {
    __shared__ float tile[64][65];
    const int ab = blockIdx.x, db = blockIdx.y;
    const int a0 = ab * 64, d0 = db * 64;
    const int t = threadIdx.x;
    const int ar = t >> 4, dc = (t & 15) * 4;
#pragma unroll
    for (int r = 0; r < 4; ++r) {
        int a = ar + r * 16;
        float ww = w[a0 + a];
        ww *= ww;
        const float4 v = *reinterpret_cast<const float4*>(E + (size_t)(a0 + a) * TOTD + d0 + dc);
        tile[a][dc + 0] = ww * v.x;
        tile[a][dc + 1] = ww * v.y;
        tile[a][dc + 2] = ww * v.z;
        tile[a][dc + 3] = ww * v.w;
    }
    __syncthreads();
    const int as = (t & 7) * 8;
#pragma unroll
    for (int r = 0; r < 2; ++r) {
        int d = (t >> 3) + r * 32;
        unsigned int lo = 0, hi = 0;
#pragma unroll
        for (int e = 0; e < 4; ++e) lo |= f32_to_e4m3(tile[as + e][d]) << (8 * e);
#pragma unroll
        for (int e = 0; e < 4; ++e) hi |= f32_to_e4m3(tile[as + 4 + e][d]) << (8 * e);
        *reinterpret_cast<uint2*>(Gt8 + (size_t)(d0 + d) * NN + a0 + as) = make_uint2(lo, hi);
    }
    if (t < 64) {
        float s = 0.f;
#pragma unroll 8
        for (int a = 0; a < 64; ++a) s += tile[a][t];
        csp[(size_t)ab * TOTD + d0 + t] = s;
    }
}

// ---- kernel 2: per-slice colsums S[16][2560] and global colmean cm[2560]
__global__ __launch_bounds__(256) void sums_k(const float* __restrict__ csp,
                                              float* __restrict__ S,
                                              float* __restrict__ cm) {
    int d = blockIdx.x * 256 + threadIdx.x;
    float tot = 0.f;
#pragma unroll
    for (int s = 0; s < 16; ++s) {
        float v = 0.f;
#pragma unroll
        for (int b = 0; b < 4; ++b) v += csp[(size_t)(s * 4 + b) * TOTD + d];
        S[(size_t)s * TOTD + d] = v;
        tot += v;
    }
    cm[d] = tot * (1.0f / NN);
}

// ---- kernel 3: 720 blocks = 45 pairs x 16 K-slices (K=256, BK=64, MX fp8).
// DIAGNOSTIC ROUND: launched TWICE (idempotent, pure function -> pp[bx]);
// dur_us delta vs round 9 = T_gram exactly. Body identical to round 9.
__global__ __launch_bounds__(512, 2) void gram_fro_k(const unsigned char* __restrict__ Gt8,
                                                     const float* __restrict__ S,
                                                     const float* __restrict__ cm,
                                                     float* __restrict__ pp) {
    const int bx = blockIdx.x;
    const int q = bx >> 3;
    const int pr = q % 45;
    const int s = (bx & 7) + 8 * (q / 45);
    int ci = 0, r0 = pr, cnt = NCH - 1;
    while (r0 >= cnt) { r0 -= cnt; --cnt; ++ci; }
    const int cj = ci + 1 + r0;
    const int k0 = s * 256;

    const int tid = threadIdx.x, wave = tid >> 6, lane = tid & 63;
    const int wm = wave >> 2, wn = wave & 3;
    const int l31 = lane & 31, h = lane >> 5;

    __shared__ char lds[65536];   // 2 bufs x [A 16K | B 16K]

    const int gslot = (lane & 3) ^ ((lane >> 3) & 3);
    const unsigned char* gA = Gt8 + (size_t)(ci * EMB + wave * 32 + (lane >> 2)) * NN + k0 + gslot * 16;
    const unsigned char* gB = Gt8 + (size_t)(cj * EMB + wave * 32 + (lane >> 2)) * NN + k0 + gslot * 16;
    const int ldsW = wave * 2048;  // 32 rows * 64 B

#define STAGE(buf, t)                                                              \
    do {                                                                           \
        _Pragma("unroll") for (int ii = 0; ii < 2; ++ii) {                         \
            gload_lds16(gA + (size_t)ii * 16 * NN + (size_t)(t) * 64,              \
                        lds + (buf) * 32768 + ldsW + ii * 1024);                   \
            gload_lds16(gB + (size_t)ii * 16 * NN + (size_t)(t) * 64,              \
                        lds + (buf) * 32768 + 16384 + ldsW + ii * 1024);           \
        }                                                                          \
    } while (0)

    f32x16 acc[4][2];
#pragma unroll
    for (int f = 0; f < 4; ++f)
#pragma unroll
        for (int g = 0; g < 2; ++g)
#pragma unroll
            for (int e = 0; e < 16; ++e) acc[f][g][e] = 0.f;

    STAGE(0, 0);
    asm volatile("s_waitcnt vmcnt(0)" ::: "memory");
    __builtin_amdgcn_s_barrier();
    __builtin_amdgcn_sched_barrier(0);

    const int x2 = (lane >> 1) & 3;
    const int sl0 = ((2 * h) ^ x2) * 16;
    const int sl1 = ((2 * h + 1) ^ x2) * 16;

#pragma unroll
    for (int t = 0; t < 4; ++t) {
        const int buf = t & 1;
        if (t < 3) STAGE(buf ^ 1, t + 1);
        const char* Ab = lds + buf * 32768;
        const char* Bb = Ab + 16384;
        i32x8 av[4], bv[2];
#pragma unroll
        for (int f = 0; f < 4; ++f) {
            const char* p = Ab + (wm * 128 + f * 32 + l31) * 64;
            i32x4 lo = *reinterpret_cast<const i32x4*>(p + sl0);
            i32x4 hi = *reinterpret_cast<const i32x4*>(p + sl1);
            av[f] = __builtin_shufflevector(lo, hi, 0, 1, 2, 3, 4, 5, 6, 7);
        }
#pragma unroll
        for (int g = 0; g < 2; ++g) {
            const char* p = Bb + (wn * 64 + g * 32 + l31) * 64;
            i32x4 lo = *reinterpret_cast<const i32x4*>(p + sl0);
            i32x4 hi = *reinterpret_cast<const i32x4*>(p + sl1);
            bv[g] = __builtin_shufflevector(lo, hi, 0, 1, 2, 3, 4, 5, 6, 7);
        }
#pragma unroll
        for (int f = 0; f < 4; ++f)
#pragma unroll
            for (int g = 0; g < 2; ++g)
                acc[f][g] = __builtin_amdgcn_mfma_scale_f32_32x32x64_f8f6f4(
                    av[f], bv[g], acc[f][g], 0, 0,
                    0, (int)0x7F7F7F7F, 0, (int)0x7F7F7F7F);
        if (t < 3) {
            asm volatile("s_waitcnt vmcnt(0)" ::: "memory");
            __builtin_amdgcn_s_barrier();
            __builtin_amdgcn_sched_barrier(0);
        }
    }
#undef STAGE

    // exact per-slice centering correction + sum of squares.
    const float* Si = S + (size_t)s * TOTD + ci * EMB;
    const float* Sj = S + (size_t)s * TOTD + cj * EMB;
    const float* ki = cm + ci * EMB;
    const float* kj = cm + cj * EMB;
    float cb[2], tb[2];
#pragma unroll
    for (int g = 0; g < 2; ++g) {
        int b = wn * 64 + g * 32 + l31;
        cb[g] = kj[b];
        tb[g] = Sj[b] - 256.f * cb[g];
    }
    float sq = 0.f;
#pragma unroll
    for (int f = 0; f < 4; ++f) {
        const int abase = wm * 128 + f * 32 + 4 * h;
#pragma unroll
        for (int qd = 0; qd < 4; ++qd) {
            const f32x4 sa = *reinterpret_cast<const f32x4*>(Si + abase + 8 * qd);
            const f32x4 ka = *reinterpret_cast<const f32x4*>(ki + abase + 8 * qd);
#pragma unroll
            for (int g = 0; g < 2; ++g)
#pragma unroll
                for (int e = 0; e < 4; ++e) {
                    float v = acc[f][g][qd * 4 + e] - sa[e] * cb[g] - ka[e] * tb[g];
                    sq += v * v;
                }
        }
    }

    __syncthreads();               // LDS buffers dead; reuse for reduction
    float* sred = (float*)lds;
    sred[tid] = sq;
    __syncthreads();
    if (tid < 64) {
        float v = 0.f;
#pragma unroll
        for (int c = 0; c < 8; ++c) v += sred[tid + c * 64];
#pragma unroll
        for (int off = 32; off > 0; off >>= 1) v += __shfl_down(v, off);
        if (tid == 0) pp[blockIdx.x] = v;
    }
}

// ---- kernel 4: deterministic final reduction
__global__ __launch_bounds__(256) void finalize_k(const float* __restrict__ pp,
                                                  float* __restrict__ out) {
    __shared__ float sh[256];
    float s = 0.f;
    for (int idx = threadIdx.x; idx < 720; idx += 256) s += pp[idx];
    sh[threadIdx.x] = s;
    __syncthreads();
    for (int stride = 128; stride > 0; stride >>= 1) {
        if (threadIdx.x < stride) sh[threadIdx.x] += sh[threadIdx.x + stride];
        __syncthreads();
    }
    if (threadIdx.x == 0) out[0] = sh[0] * (1.0f / (4095.0f * 4095.0f));
}

extern "C" void kernel_launch(void* const* d_in, const int* in_sizes, int n_in,
                              void* d_out, int out_size, void* d_ws, size_t ws_size,
                              hipStream_t stream) {
    const float* E = (const float*)d_in[0];   // [4096, 2560] f32
    const float* w = (const float*)d_in[1];   // [4096, 1] f32
    float* out = (float*)d_out;
    char* ws = (char*)d_ws;

    // ws layout (bytes):
    //   Gt8 : 0         .. 10485760   (2560 x 4096 fp8 e4m3)
    //   csp : 10485760  .. 11141120   (64 x 2560 f32)
    //   S   : 11141120  .. 11304960   (16 x 2560 f32)
    //   cm  : 11304960  .. 11315200   (2560 f32)
    //   pp  : 11315200  .. 11318080   (720 f32)
    unsigned char* Gt8 = (unsigned char*)ws;
    float* csp = (float*)(ws + (size_t)10485760);
    float* S   = (float*)(ws + (size_t)11141120);
    float* cm  = (float*)(ws + (size_t)11304960);
    float* pp  = (float*)(ws + (size_t)11315200);

    prep_k<<<dim3(64, 40), 256, 0, stream>>>(E, w, Gt8, csp);
    sums_k<<<10, 256, 0, stream>>>(csp, S, cm);
    // DIAGNOSTIC: gram launched twice (idempotent). dur_us - 41.1 = T_gram.
    gram_fro_k<<<720, 512, 0, stream>>>(Gt8, S, cm, pp);
    gram_fro_k<<<720, 512, 0, stream>>>(Gt8, S, cm, pp);
    finalize_k<<<1, 256, 0, stream>>>(pp, out);
}

// Round 11
// 39.501 us; speedup vs baseline: 1.5044x; 1.5044x over previous
//
#include <hip/hip_runtime.h>
#include <hip/hip_bf16.h>

#define NN 4096
#define EMB 256
#define NCH 10
#define TOTD 2560  // NCH*EMB

typedef __attribute__((ext_vector_type(4))) float f32x4;
typedef __attribute__((ext_vector_type(16))) float f32x16;
typedef __attribute__((ext_vector_type(4))) int i32x4;
typedef __attribute__((ext_vector_type(8))) int i32x8;

#define AS1 __attribute__((address_space(1)))
#define AS3 __attribute__((address_space(3)))

// Gt8 layout: [kblk 0..63][d 0..2559][64 bytes]  (kblk = a>>6, byte = a&63)
#define KSTRIP 163840  // 2560 * 64

__device__ __forceinline__ void gload_lds16(const void* g, void* l) {
    __builtin_amdgcn_global_load_lds((const AS1 unsigned int*)g,
                                     (AS3 unsigned int*)l, 16, 0, 0);
}

// float -> OCP e4m3fn, RNE, flush |x| < 2^-6 (min normal) to 0.
__device__ __forceinline__ unsigned int f32_to_e4m3(float x) {
    unsigned int u = __float_as_uint(x);
    if ((u & 0x7FFFFFFFu) < 0x3C800000u) return 0u;   // |x| < 2^-6
    unsigned int r = u + 0x7FFFFu + ((u >> 20) & 1u); // RNE to 3 mantissa bits
    unsigned int s = (u >> 31) << 7;
    unsigned int e = (r >> 23) & 0xFFu;
    unsigned int m3 = (r >> 20) & 7u;
    return s | ((e - 120u) << 3) | m3;
}

// ---- kernel 1 (fused prep): one pass over E.
// F = w^2*E ; Gt8[a>>6][d][a&63] = e4m3(F[a][d]) ; csp[ablk][d] = partial colsum
__global__ __launch_bounds__(256) void prep_k(const float* __restrict__ E,
                                              const float* __restrict__ w,
                                              unsigned char* __restrict__ Gt8,
                                              float* __restrict__ csp) {
    __shared__ float tile[64][65];
    const int ab = blockIdx.x, db = blockIdx.y;
    const int a0 = ab * 64, d0 = db * 64;
    const int t = threadIdx.x;
    const int ar = t >> 4, dc = (t & 15) * 4;
#pragma unroll
    for (int r = 0; r < 4; ++r) {
        int a = ar + r * 16;
        float ww = w[a0 + a];
        ww *= ww;
        const float4 v = *reinterpret_cast<const float4*>(E + (size_t)(a0 + a) * TOTD + d0 + dc);
        tile[a][dc + 0] = ww * v.x;
        tile[a][dc + 1] = ww * v.y;
        tile[a][dc + 2] = ww * v.z;
        tile[a][dc + 3] = ww * v.w;
    }
    __syncthreads();
    const int as = (t & 7) * 8;
    const size_t kbase = (size_t)(a0 >> 6) * KSTRIP;   // a0 is a multiple of 64
#pragma unroll
    for (int r = 0; r < 2; ++r) {
        int d = (t >> 3) + r * 32;
        unsigned int lo = 0, hi = 0;
#pragma unroll
        for (int e = 0; e < 4; ++e) lo |= f32_to_e4m3(tile[as + e][d]) << (8 * e);
#pragma unroll
        for (int e = 0; e < 4; ++e) hi |= f32_to_e4m3(tile[as + 4 + e][d]) << (8 * e);
        *reinterpret_cast<uint2*>(Gt8 + kbase + (size_t)(d0 + d) * 64 + as) = make_uint2(lo, hi);
    }
    if (t < 64) {
        float s = 0.f;
#pragma unroll 8
        for (int a = 0; a < 64; ++a) s += tile[a][t];
        csp[(size_t)ab * TOTD + d0 + t] = s;
    }
}

// ---- kernel 2: per-slice colsums S[16][2560] and global colmean cm[2560]
__global__ __launch_bounds__(256) void sums_k(const float* __restrict__ csp,
                                              float* __restrict__ S,
                                              float* __restrict__ cm) {
    int d = blockIdx.x * 256 + threadIdx.x;
    float tot = 0.f;
#pragma unroll
    for (int s = 0; s < 16; ++s) {
        float v = 0.f;
#pragma unroll
        for (int b = 0; b < 4; ++b) v += csp[(size_t)(s * 4 + b) * TOTD + d];
        S[(size_t)s * TOTD + d] = v;
        tot += v;
    }
    cm[d] = tot * (1.0f / NN);
}

// ---- kernel 3: 720 blocks = 45 pairs x 16 K-slices (K=256, BK=64, MX fp8).
// r9 structure; Gt8 now slice-major so each staging step reads ONE contiguous
// 16 KB strip per matrix (full 128B-line utilization, burst-friendly).
__global__ __launch_bounds__(512, 2) void gram_fro_k(const unsigned char* __restrict__ Gt8,
                                                     const float* __restrict__ S,
                                                     const float* __restrict__ cm,
                                                     float* __restrict__ pp) {
    const int bx = blockIdx.x;
    const int q = bx >> 3;
    const int pr = q % 45;
    const int s = (bx & 7) + 8 * (q / 45);
    int ci = 0, r0 = pr, cnt = NCH - 1;
    while (r0 >= cnt) { r0 -= cnt; --cnt; ++ci; }
    const int cj = ci + 1 + r0;

    const int tid = threadIdx.x, wave = tid >> 6, lane = tid & 63;
    const int wm = wave >> 2, wn = wave & 3;
    const int l31 = lane & 31, h = lane >> 5;

    __shared__ char lds[65536];   // 2 bufs x [A 16K | B 16K]

    // staging: issue ii covers rows wave*32 + ii*16 + (lane>>2), lds slot lane&3.
    // pre-swizzled source slot: (lane&3) ^ ((row>>1)&3) = (lane&3)^((lane>>3)&3)
    // source offset within strip == (lds row)*64 + gslot*16  (global rows now 64B!)
    const int gslot = (lane & 3) ^ ((lane >> 3) & 3);
    const int rowoff = (wave * 32 + (lane >> 2)) * 64 + gslot * 16;
    const unsigned char* gA = Gt8 + (size_t)(4 * s) * KSTRIP + (size_t)ci * 256 * 64 + rowoff;
    const unsigned char* gB = Gt8 + (size_t)(4 * s) * KSTRIP + (size_t)cj * 256 * 64 + rowoff;
    const int ldsW = wave * 2048;  // 32 rows * 64 B

#define STAGE(buf, t)                                                              \
    do {                                                                           \
        _Pragma("unroll") for (int ii = 0; ii < 2; ++ii) {                         \
            gload_lds16(gA + (size_t)(t) * KSTRIP + ii * 1024,                     \
                        lds + (buf) * 32768 + ldsW + ii * 1024);                   \
            gload_lds16(gB + (size_t)(t) * KSTRIP + ii * 1024,                     \
                        lds + (buf) * 32768 + 16384 + ldsW + ii * 1024);           \
        }                                                                          \
    } while (0)

    f32x16 acc[4][2];
#pragma unroll
    for (int f = 0; f < 4; ++f)
#pragma unroll
        for (int g = 0; g < 2; ++g)
#pragma unroll
            for (int e = 0; e < 16; ++e) acc[f][g][e] = 0.f;

    STAGE(0, 0);
    asm volatile("s_waitcnt vmcnt(0)" ::: "memory");
    __builtin_amdgcn_s_barrier();
    __builtin_amdgcn_sched_barrier(0);

    // read-side swizzle: x = (row>>1)&3 = (lane>>1)&3 (row base mult of 32)
    const int x2 = (lane >> 1) & 3;
    const int sl0 = ((2 * h) ^ x2) * 16;
    const int sl1 = ((2 * h + 1) ^ x2) * 16;

#pragma unroll
    for (int t = 0; t < 4; ++t) {
        const int buf = t & 1;
        if (t < 3) STAGE(buf ^ 1, t + 1);
        const char* Ab = lds + buf * 32768;
        const char* Bb = Ab + 16384;
        i32x8 av[4], bv[2];
#pragma unroll
        for (int f = 0; f < 4; ++f) {
            const char* p = Ab + (wm * 128 + f * 32 + l31) * 64;
            i32x4 lo = *reinterpret_cast<const i32x4*>(p + sl0);
            i32x4 hi = *reinterpret_cast<const i32x4*>(p + sl1);
            av[f] = __builtin_shufflevector(lo, hi, 0, 1, 2, 3, 4, 5, 6, 7);
        }
#pragma unroll
        for (int g = 0; g < 2; ++g) {
            const char* p = Bb + (wn * 64 + g * 32 + l31) * 64;
            i32x4 lo = *reinterpret_cast<const i32x4*>(p + sl0);
            i32x4 hi = *reinterpret_cast<const i32x4*>(p + sl1);
            bv[g] = __builtin_shufflevector(lo, hi, 0, 1, 2, 3, 4, 5, 6, 7);
        }
#pragma unroll
        for (int f = 0; f < 4; ++f)
#pragma unroll
            for (int g = 0; g < 2; ++g)
                acc[f][g] = __builtin_amdgcn_mfma_scale_f32_32x32x64_f8f6f4(
                    av[f], bv[g], acc[f][g], 0, 0,
                    0, (int)0x7F7F7F7F, 0, (int)0x7F7F7F7F);
        if (t < 3) {
            asm volatile("s_waitcnt vmcnt(0)" ::: "memory");
            __builtin_amdgcn_s_barrier();
            __builtin_amdgcn_sched_barrier(0);
        }
    }
#undef STAGE

    // exact per-slice centering correction + sum of squares.
    // C/D 32x32 mapping (HW-verified m74/m101, dtype-independent m121-128):
    //   a_row = (reg&3) + 8*(reg>>2) + 4*(lane>>5), b_col = lane&31
    const float* Si = S + (size_t)s * TOTD + ci * EMB;
    const float* Sj = S + (size_t)s * TOTD + cj * EMB;
    const float* ki = cm + ci * EMB;
    const float* kj = cm + cj * EMB;
    float cb[2], tb[2];
#pragma unroll
    for (int g = 0; g < 2; ++g) {
        int b = wn * 64 + g * 32 + l31;
        cb[g] = kj[b];
        tb[g] = Sj[b] - 256.f * cb[g];
    }
    float sq = 0.f;
#pragma unroll
    for (int f = 0; f < 4; ++f) {
        const int abase = wm * 128 + f * 32 + 4 * h;
#pragma unroll
        for (int qd = 0; qd < 4; ++qd) {
            const f32x4 sa = *reinterpret_cast<const f32x4*>(Si + abase + 8 * qd);
            const f32x4 ka = *reinterpret_cast<const f32x4*>(ki + abase + 8 * qd);
#pragma unroll
            for (int g = 0; g < 2; ++g)
#pragma unroll
                for (int e = 0; e < 4; ++e) {
                    float v = acc[f][g][qd * 4 + e] - sa[e] * cb[g] - ka[e] * tb[g];
                    sq += v * v;
                }
        }
    }

    __syncthreads();               // LDS buffers dead; reuse for reduction
    float* sred = (float*)lds;
    sred[tid] = sq;
    __syncthreads();
    if (tid < 64) {
        float v = 0.f;
#pragma unroll
        for (int c = 0; c < 8; ++c) v += sred[tid + c * 64];
#pragma unroll
        for (int off = 32; off > 0; off >>= 1) v += __shfl_down(v, off);
        if (tid == 0) pp[blockIdx.x] = v;
    }
}

// ---- kernel 4: deterministic final reduction
__global__ __launch_bounds__(256) void finalize_k(const float* __restrict__ pp,
                                                  float* __restrict__ out) {
    __shared__ float sh[256];
    float s = 0.f;
    for (int idx = threadIdx.x; idx < 720; idx += 256) s += pp[idx];
    sh[threadIdx.x] = s;
    __syncthreads();
    for (int stride = 128; stride > 0; stride >>= 1) {
        if (threadIdx.x < stride) sh[threadIdx.x] += sh[threadIdx.x + stride];
        __syncthreads();
    }
    if (threadIdx.x == 0) out[0] = sh[0] * (1.0f / (4095.0f * 4095.0f));
}

extern "C" void kernel_launch(void* const* d_in, const int* in_sizes, int n_in,
                              void* d_out, int out_size, void* d_ws, size_t ws_size,
                              hipStream_t stream) {
    const float* E = (const float*)d_in[0];   // [4096, 2560] f32
    const float* w = (const float*)d_in[1];   // [4096, 1] f32
    float* out = (float*)d_out;
    char* ws = (char*)d_ws;

    // ws layout (bytes):
    //   Gt8 : 0         .. 10485760   (64 kblks x 2560 d x 64 B, fp8 e4m3)
    //   csp : 10485760  .. 11141120   (64 x 2560 f32)
    //   S   : 11141120  .. 11304960   (16 x 2560 f32)
    //   cm  : 11304960  .. 11315200   (2560 f32)
    //   pp  : 11315200  .. 11318080   (720 f32)
    unsigned char* Gt8 = (unsigned char*)ws;
    float* csp = (float*)(ws + (size_t)10485760);
    float* S   = (float*)(ws + (size_t)11141120);
    float* cm  = (float*)(ws + (size_t)11304960);
    float* pp  = (float*)(ws + (size_t)11315200);

    prep_k<<<dim3(64, 40), 256, 0, stream>>>(E, w, Gt8, csp);
    sums_k<<<10, 256, 0, stream>>>(csp, S, cm);
    gram_fro_k<<<720, 512, 0, stream>>>(Gt8, S, cm, pp);
    finalize_k<<<1, 256, 0, stream>>>(pp, out);
}